// Round 5
// baseline (53.077 us; speedup 1.0000x reference)
//
#include <hip/hip_runtime.h>
#include <math.h>

#define NQ_     14
#define DIM_    16384
#define NB      256
#define NLAYERS 3
#define NPAIR   13
#define NT      1024

// LDS swizzle: XOR bits 1-3 of the float2 index with bits 4-6.
#define SW(k) ((k) ^ ((((k) >> 4) & 7) << 1))

__device__ __forceinline__ float2 cmul(float2 a, float2 b) {
    return make_float2(a.x*b.x - a.y*b.y, a.x*b.y + a.y*b.x);
}

__device__ __forceinline__ void g2(float2& a0, float2& a1,
        float2 u00, float2 u01, float2 u10, float2 u11) {
    float2 b0, b1;
    b0.x = u00.x*a0.x - u00.y*a0.y + u01.x*a1.x - u01.y*a1.y;
    b0.y = u00.x*a0.y + u00.y*a0.x + u01.x*a1.y + u01.y*a1.x;
    b1.x = u10.x*a0.x - u10.y*a0.y + u11.x*a1.x - u11.y*a1.y;
    b1.y = u10.x*a0.y + u10.y*a0.x + u11.x*a1.y + u11.y*a1.x;
    a0 = b0; a1 = b1;
}

#define GATE_BIT(RB, Uptr) do { \
    float2 u00 = (Uptr)[0], u01 = (Uptr)[1], u10 = (Uptr)[2], u11 = (Uptr)[3]; \
    _Pragma("unroll") \
    for (int j = 0; j < 16; ++j) \
        if (!((j >> (RB)) & 1)) g2(a[j], a[j | (1 << (RB))], u00, u01, u10, u11); \
} while (0)

__global__ __launch_bounds__(NT, 1) void pqc_kernel(
    const float* __restrict__ x,     // (256, 28)
    const float* __restrict__ psq,   // (3, 2, 14, 3)
    const float* __restrict__ p2q,   // (3, 196)
    const float* __restrict__ penc,  // (3, 196)
    const float* __restrict__ pcl,   // (14,)
    float* __restrict__ out)         // (256,)
{
    __shared__ __align__(16) float2 s_amp[DIM_];   // 128 KiB state
    __shared__ float2 s_U[4][NQ_][4];              // merged gate sets (set3 kept for observable rotation)
    __shared__ float2 s_C0[2][128];                // diag cis (layers 0,1; low 7 xor-bits)
    __shared__ float2 s_C1[2][64];                 // diag cis (layers 0,1; high bits, -S/2 folded)
    __shared__ float2 s_WE[NQ_][4];                // 2*W_bp*cis(dphi(s)) per bit, s=(k_{bp+1}<<1)|k_{bp-1}
    __shared__ float  s_G[NQ_];                    // gamma_bp (Z coefficient after set3 rotation)
    __shared__ float  s_theta[NLAYERS][NPAIR];
    __shared__ float  s_red[16];

    const int n = blockIdx.x;
    const int t = threadIdx.x;

    // ---------- phase 1: theta + merged gate matrices ----------
    if (t < NLAYERS * NPAIR) {
        int l = t / NPAIR, p = t - l * NPAIR;
        const float* xr = x + n * 28;
        float feat = xr[2*p] * xr[2*p+2] + xr[2*p+1] * xr[2*p+3];
        int pf = 15 * p + 1;
        s_theta[l][p] = p2q[l*196 + pf] + penc[l*196 + pf] * feat;
    } else if (t >= 64 && t < 64 + 4 * NQ_) {
        // set0 = U0(L0); set1 = U0(L1)*U1(L0); set2 = U0(L2)*U1(L1); set3 = U1(L2)
        int j = t - 64;
        int set = j / NQ_;
        int q = j - set * NQ_;
        auto build = [&](int l, int s, float2 Uo[4]) {
            const float* a = psq + ((l * 2 + s) * NQ_ + q) * 3;
            float phi = a[0], th = a[1], om = a[2];
            float sh, ch; sincosf(0.5f * th, &sh, &ch);
            float sa, ca; sincosf(0.5f * (phi + om), &sa, &ca);
            float sb, cb; sincosf(0.5f * (phi - om), &sb, &cb);
            Uo[0] = make_float2( ch * ca, -ch * sa);
            Uo[1] = make_float2(-sh * cb, -sh * sb);
            Uo[2] = make_float2( sh * cb, -sh * sb);
            Uo[3] = make_float2( ch * ca,  ch * sa);
        };
        float2 M[4];
        if (set == 0) {
            build(0, 0, M);
        } else if (set == 3) {
            build(2, 1, M);
        } else {
            float2 A[4], Bm[4];
            build(set, 0, A);        // second
            build(set - 1, 1, Bm);   // first
            M[0].x = A[0].x*Bm[0].x - A[0].y*Bm[0].y + A[1].x*Bm[2].x - A[1].y*Bm[2].y;
            M[0].y = A[0].x*Bm[0].y + A[0].y*Bm[0].x + A[1].x*Bm[2].y + A[1].y*Bm[2].x;
            M[1].x = A[0].x*Bm[1].x - A[0].y*Bm[1].y + A[1].x*Bm[3].x - A[1].y*Bm[3].y;
            M[1].y = A[0].x*Bm[1].y + A[0].y*Bm[1].x + A[1].x*Bm[3].y + A[1].y*Bm[3].x;
            M[2].x = A[2].x*Bm[0].x - A[2].y*Bm[0].y + A[3].x*Bm[2].x - A[3].y*Bm[2].y;
            M[2].y = A[2].x*Bm[0].y + A[2].y*Bm[0].x + A[3].x*Bm[2].y + A[3].y*Bm[2].x;
            M[3].x = A[2].x*Bm[1].x - A[2].y*Bm[1].y + A[3].x*Bm[3].x - A[3].y*Bm[3].y;
            M[3].y = A[2].x*Bm[1].y + A[2].y*Bm[1].x + A[3].x*Bm[3].y + A[3].y*Bm[3].x;
        }
        #pragma unroll
        for (int e = 0; e < 4; ++e) s_U[set][q][e] = M[e];
    }
    __syncthreads();

    // ---------- phase 2: diag cis tables (layers 0,1) + observable tables ----------
    if (t < 256) {
        int l = t >> 7, i = t & 127;
        float v = 0.0f;
        #pragma unroll
        for (int b = 0; b < 7; ++b)
            if ((i >> b) & 1) v += s_theta[l][12 - b];
        float sn, cs; sincosf(v, &sn, &cs);
        s_C0[l][i] = make_float2(cs, sn);
    } else if (t < 384) {
        int j = t - 256;
        int l = j >> 6, h = j & 63;
        float S = 0.0f;
        #pragma unroll
        for (int p = 0; p < NPAIR; ++p) S += s_theta[l][p];
        float v = -0.5f * S;
        #pragma unroll
        for (int b = 7; b < 13; ++b)
            if ((h >> (b - 7)) & 1) v += s_theta[l][12 - b];
        float sn, cs; sincosf(v, &sn, &cs);
        s_C1[l][h] = make_float2(cs, sn);
    } else if (t < 440) {
        // WE[bp][s] = 2 * W_bp * cis(dphi), W = set3-rotated off-diagonal coefficient
        int idx = t - 384, bp = idx >> 2, s = idx & 3;
        int q = 13 - bp;
        float2 v00 = s_U[3][q][0], v01 = s_U[3][q][1];
        float2 v10 = s_U[3][q][2], v11 = s_U[3][q][3];
        float cz = pcl[q], cx = pcl[bp];
        // t1 = conj(v00)*v01 - conj(v10)*v11 ; t2 = conj(v00)*v11 + conj(v10)*v01
        float t1x = (v00.x*v01.x + v00.y*v01.y) - (v10.x*v11.x + v10.y*v11.y);
        float t1y = (v00.x*v01.y - v00.y*v01.x) - (v10.x*v11.y - v10.y*v11.x);
        float t2x = (v00.x*v11.x + v00.y*v11.y) + (v10.x*v01.x + v10.y*v01.y);
        float t2y = (v00.x*v11.y - v00.y*v11.x) + (v10.x*v01.y - v10.y*v01.x);
        float Wx = cz*t1x + cx*t2x, Wy = cz*t1y + cx*t2y;
        float tha = (bp <= 12) ? s_theta[2][12 - bp] : 0.f;
        float thb = (bp >= 1)  ? s_theta[2][13 - bp] : 0.f;
        float dphi = tha * (1.f - 2.f*((s >> 1) & 1)) + thb * (1.f - 2.f*(s & 1));
        float sn, cs; sincosf(dphi, &sn, &cs);
        s_WE[bp][s] = make_float2(2.f*(Wx*cs - Wy*sn), 2.f*(Wx*sn + Wy*cs));
    } else if (t >= 448 && t < 462) {
        int bp = t - 448, q = 13 - bp;
        float2 v00 = s_U[3][q][0], v10 = s_U[3][q][2];
        float cz = pcl[q], cx = pcl[bp];
        s_G[bp] = cz * ((v00.x*v00.x + v00.y*v00.y) - (v10.x*v10.x + v10.y*v10.y))
                + 2.f*cx * (v00.x*v10.x + v00.y*v10.y);
    }
    __syncthreads();

    float2 a[16];
    float acc = 0.0f;

    // ---- layouts A(bits0-3), B(4-7), C(8-11), D(12,13,0,1), E(2,3,7,11) ----
#define LOAD_A() do { _Pragma("unroll") for (int c = 0; c < 8; ++c) { \
        int p = SW((t << 4) | (2*c)); \
        float4 v = *(const float4*)&s_amp[p]; \
        a[2*c] = make_float2(v.x, v.y); a[2*c+1] = make_float2(v.z, v.w); } } while (0)
#define STORE_A() do { _Pragma("unroll") for (int c = 0; c < 8; ++c) { \
        int p = SW((t << 4) | (2*c)); \
        *(float4*)&s_amp[p] = make_float4(a[2*c].x, a[2*c].y, a[2*c+1].x, a[2*c+1].y); } } while (0)
#define LOAD_B() do { int bb = ((t >> 4) << 8) | (t & 15); _Pragma("unroll") \
        for (int j = 0; j < 16; ++j) a[j] = s_amp[SW(bb | (j << 4))]; } while (0)
#define STORE_B() do { int bb = ((t >> 4) << 8) | (t & 15); _Pragma("unroll") \
        for (int j = 0; j < 16; ++j) s_amp[SW(bb | (j << 4))] = a[j]; } while (0)
#define LOAD_C() do { int bc = ((t >> 8) << 12) | (t & 255); _Pragma("unroll") \
        for (int j = 0; j < 16; ++j) a[j] = s_amp[SW(bc | (j << 8))]; } while (0)
#define STORE_C() do { int bc = ((t >> 8) << 12) | (t & 255); _Pragma("unroll") \
        for (int j = 0; j < 16; ++j) s_amp[SW(bc | (j << 8))] = a[j]; } while (0)
#define LOAD_D() do { _Pragma("unroll") for (int jh = 0; jh < 4; ++jh) \
        _Pragma("unroll") for (int c = 0; c < 2; ++c) { \
        int p = SW((jh << 12) | (t << 2) | (2*c)); \
        float4 v = *(const float4*)&s_amp[p]; \
        a[jh*4+2*c] = make_float2(v.x, v.y); a[jh*4+2*c+1] = make_float2(v.z, v.w); } } while (0)
#define STORE_D() do { _Pragma("unroll") for (int jh = 0; jh < 4; ++jh) \
        _Pragma("unroll") for (int c = 0; c < 2; ++c) { \
        int p = SW((jh << 12) | (t << 2) | (2*c)); \
        *(float4*)&s_amp[p] = make_float4(a[jh*4+2*c].x, a[jh*4+2*c].y, a[jh*4+2*c+1].x, a[jh*4+2*c+1].y); } } while (0)
#define LOAD_E() do { \
        int kb = (t & 3) | (((t >> 2) & 7) << 4) | (((t >> 5) & 7) << 8) | (((t >> 8) & 3) << 12); \
        _Pragma("unroll") for (int j = 0; j < 16; ++j) { \
            int k = kb | ((j & 3) << 2) | (((j >> 2) & 1) << 7) | (((j >> 3) & 1) << 11); \
            a[j] = s_amp[SW(k)]; } } while (0)

#define DIAG(l, KEXPR) do { _Pragma("unroll") for (int j = 0; j < 16; ++j) { \
        int k = (KEXPR); int m = k ^ (k >> 1); \
        float2 ph = cmul(s_C0[l][m & 127], s_C1[l][(m >> 7) & 63]); \
        a[j] = cmul(a[j], ph); } } while (0)

#define PRCOMP() do { _Pragma("unroll") for (int j = 0; j < 16; ++j) \
        pr[j] = a[j].x*a[j].x + a[j].y*a[j].y; } while (0)

    // Measure bit bp at register bit RB: Z part (gamma) + phase-corrected X/Y part (WE).
    // NHI/NLO = values of state bits bp+1 / bp-1 (expressions in j and t).
#define MEAS(BP, RB, NHI, NLO) do { \
    float g = s_G[BP]; float zs = 0.f, xr = 0.f; \
    const float2* WEp = s_WE[BP]; \
    _Pragma("unroll") for (int j = 0; j < 16; ++j) { \
        if (!((j >> (RB)) & 1)) { \
            int j1 = j | (1 << (RB)); \
            float cr = a[j].x*a[j1].x + a[j].y*a[j1].y; \
            float ci = a[j].x*a[j1].y - a[j].y*a[j1].x; \
            float2 w = WEp[((NHI) << 1) | (NLO)]; \
            xr += w.x * cr - w.y * ci; \
            zs += pr[j] - pr[j1]; \
        } } \
    acc += g * zs + xr; \
} while (0)

    // ---- P1 (D): analytic set0 product state, diag0, set1 gates bits12,13 ----
    {
        float2 F = make_float2(1.f, 0.f);
        #pragma unroll
        for (int bp = 2; bp < 12; ++bp) {
            int b = (t >> (bp - 2)) & 1;
            float2 f = s_U[0][13 - bp][b ? 2 : 0];
            F = cmul(F, f);
        }
        float2 g01[4], g23[4];
        #pragma unroll
        for (int j1 = 0; j1 < 2; ++j1)
            #pragma unroll
            for (int j0 = 0; j0 < 2; ++j0)
                g01[(j1 << 1) | j0] = cmul(s_U[0][13][j0 ? 2 : 0], s_U[0][12][j1 ? 2 : 0]);
        #pragma unroll
        for (int j3 = 0; j3 < 2; ++j3)
            #pragma unroll
            for (int j2 = 0; j2 < 2; ++j2)
                g23[(j3 << 1) | j2] = cmul(s_U[0][1][j2 ? 2 : 0], s_U[0][0][j3 ? 2 : 0]);
        float2 Fg[4];
        #pragma unroll
        for (int jl = 0; jl < 4; ++jl) Fg[jl] = cmul(F, g01[jl]);
        #pragma unroll
        for (int j = 0; j < 16; ++j) a[j] = cmul(Fg[j & 3], g23[j >> 2]);
    }
    DIAG(0, ((j >> 2) << 12) | (t << 2) | (j & 3));
    GATE_BIT(2, s_U[1][1]);   // bit12 -> qubit 1
    GATE_BIT(3, s_U[1][0]);   // bit13 -> qubit 0
    STORE_D(); __syncthreads();

    // ---- P2 (C): set1 bits 8-11 ----
    LOAD_C();
    GATE_BIT(0, s_U[1][5]); GATE_BIT(1, s_U[1][4]);
    GATE_BIT(2, s_U[1][3]); GATE_BIT(3, s_U[1][2]);
    STORE_C(); __syncthreads();

    // ---- P3 (B): set1 bits 4-7 ----
    LOAD_B();
    GATE_BIT(0, s_U[1][9]); GATE_BIT(1, s_U[1][8]);
    GATE_BIT(2, s_U[1][7]); GATE_BIT(3, s_U[1][6]);
    STORE_B(); __syncthreads();

    // ---- P4 (A): set1 bits 0-3, diag1, set2 bits 0-3, measure bits 0-2 ----
    LOAD_A();
    GATE_BIT(0, s_U[1][13]); GATE_BIT(1, s_U[1][12]);
    GATE_BIT(2, s_U[1][11]); GATE_BIT(3, s_U[1][10]);
    DIAG(1, (t << 4) | j);
    GATE_BIT(0, s_U[2][13]); GATE_BIT(1, s_U[2][12]);
    GATE_BIT(2, s_U[2][11]); GATE_BIT(3, s_U[2][10]);
    {
        float pr[16]; PRCOMP();
        MEAS(0, 0, ((j >> 1) & 1), 0);
        MEAS(1, 1, ((j >> 2) & 1), (j & 1));
        MEAS(2, 2, ((j >> 3) & 1), ((j >> 1) & 1));
    }
    STORE_A(); __syncthreads();

    // ---- P5 (B): set2 bits 4-7, measure bits 4-6 ----
    LOAD_B();
    GATE_BIT(0, s_U[2][9]); GATE_BIT(1, s_U[2][8]);
    GATE_BIT(2, s_U[2][7]); GATE_BIT(3, s_U[2][6]);
    {
        float pr[16]; PRCOMP();
        MEAS(4, 0, ((j >> 1) & 1), ((t >> 3) & 1));
        MEAS(5, 1, ((j >> 2) & 1), (j & 1));
        MEAS(6, 2, ((j >> 3) & 1), ((j >> 1) & 1));
    }
    STORE_B(); __syncthreads();

    // ---- P6 (C): set2 bits 8-11, measure bits 8-10 ----
    LOAD_C();
    GATE_BIT(0, s_U[2][5]); GATE_BIT(1, s_U[2][4]);
    GATE_BIT(2, s_U[2][3]); GATE_BIT(3, s_U[2][2]);
    {
        float pr[16]; PRCOMP();
        MEAS(8, 0, ((j >> 1) & 1), ((t >> 7) & 1));
        MEAS(9, 1, ((j >> 2) & 1), (j & 1));
        MEAS(10, 2, ((j >> 3) & 1), ((j >> 1) & 1));
    }
    STORE_C(); __syncthreads();

    // ---- P7 (D): set2 bits 12,13, measure bits 12,13 ----
    LOAD_D();
    GATE_BIT(2, s_U[2][1]); GATE_BIT(3, s_U[2][0]);
    {
        float pr[16]; PRCOMP();
        MEAS(12, 2, ((j >> 3) & 1), ((t >> 9) & 1));
        MEAS(13, 3, 0, ((j >> 2) & 1));
    }
    STORE_D(); __syncthreads();

    // ---- P8 (E: bits 2,3,7,11): measure bits 3,7,11 (load only) ----
    LOAD_E();
    {
        float pr[16]; PRCOMP();
        MEAS(3,  1, ((t >> 2) & 1), (j & 1));
        MEAS(7,  2, ((t >> 5) & 1), ((t >> 4) & 1));
        MEAS(11, 3, ((t >> 8) & 1), ((t >> 7) & 1));
    }

    // ---- block reduction ----
    #pragma unroll
    for (int off = 32; off > 0; off >>= 1)
        acc += __shfl_down(acc, off);
    if ((t & 63) == 0) s_red[t >> 6] = acc;
    __syncthreads();
    if (t == 0) {
        float s = 0.0f;
        #pragma unroll
        for (int w = 0; w < 16; ++w) s += s_red[w];
        out[n] = s;
    }
}

extern "C" void kernel_launch(void* const* d_in, const int* in_sizes, int n_in,
                              void* d_out, int out_size, void* d_ws, size_t ws_size,
                              hipStream_t stream) {
    const float* x    = (const float*)d_in[0];
    const float* psq  = (const float*)d_in[1];
    const float* p2q  = (const float*)d_in[2];
    const float* penc = (const float*)d_in[3];
    const float* pcl  = (const float*)d_in[4];
    float* out = (float*)d_out;
    pqc_kernel<<<NB, NT, 0, stream>>>(x, psq, p2q, penc, pcl, out);
}

// Round 6
// 38.915 us; speedup vs baseline: 1.3639x; 1.3639x over previous
//
#include <hip/hip_runtime.h>
#include <math.h>

#define NQ_     14
#define DIM_    16384
#define NB      256
#define NLAYERS 3
#define NPAIR   13
#define NT      1024

// LDS swizzle: XOR bits 1-3 of the float2 index with bits 4-6.
#define SW(k) ((k) ^ ((((k) >> 4) & 7) << 1))

__device__ __forceinline__ float2 cmul(float2 a, float2 b) {
    return make_float2(a.x*b.x - a.y*b.y, a.x*b.y + a.y*b.x);
}

__device__ __forceinline__ void g2(float2& a0, float2& a1,
        float2 u00, float2 u01, float2 u10, float2 u11) {
    float2 b0, b1;
    b0.x = u00.x*a0.x - u00.y*a0.y + u01.x*a1.x - u01.y*a1.y;
    b0.y = u00.x*a0.y + u00.y*a0.x + u01.x*a1.y + u01.y*a1.x;
    b1.x = u10.x*a0.x - u10.y*a0.y + u11.x*a1.x - u11.y*a1.y;
    b1.y = u10.x*a0.y + u10.y*a0.x + u11.x*a1.y + u11.y*a1.x;
    a0 = b0; a1 = b1;
}

#define GATE_BIT(RB, Uptr) do { \
    float2 u00 = (Uptr)[0], u01 = (Uptr)[1], u10 = (Uptr)[2], u11 = (Uptr)[3]; \
    _Pragma("unroll") \
    for (int j = 0; j < 16; ++j) \
        if (!((j >> (RB)) & 1)) g2(a[j], a[j | (1 << (RB))], u00, u01, u10, u11); \
} while (0)

__global__ __launch_bounds__(NT, 4) void pqc_kernel(
    const float* __restrict__ x,     // (256, 28)
    const float* __restrict__ psq,   // (3, 2, 14, 3)
    const float* __restrict__ p2q,   // (3, 196)
    const float* __restrict__ penc,  // (3, 196)
    const float* __restrict__ pcl,   // (14,)
    float* __restrict__ out)         // (256,)
{
    __shared__ __align__(16) float2 s_amp[DIM_];   // 128 KiB state
    __shared__ float2 s_U[4][NQ_][4];              // merged gate sets (set3 kept for observable rotation)
    __shared__ float2 s_C0[2][128];                // diag cis (layers 0,1; low 7 xor-bits)
    __shared__ float2 s_C1[2][64];                 // diag cis (layers 0,1; high bits, -S/2 folded)
    __shared__ float2 s_WE[NQ_][4];                // 2*W_bp*cis(dphi(s)) per bit, s=(k_{bp+1}<<1)|k_{bp-1}
    __shared__ float  s_G[NQ_];                    // gamma_bp (Z coefficient after set3 rotation)
    __shared__ float  s_theta[NLAYERS][NPAIR];
    __shared__ float  s_red[16];

    const int n = blockIdx.x;
    const int t = threadIdx.x;

    // ---------- phase 1: theta + merged gate matrices ----------
    if (t < NLAYERS * NPAIR) {
        int l = t / NPAIR, p = t - l * NPAIR;
        const float* xr = x + n * 28;
        float feat = xr[2*p] * xr[2*p+2] + xr[2*p+1] * xr[2*p+3];
        int pf = 15 * p + 1;
        s_theta[l][p] = p2q[l*196 + pf] + penc[l*196 + pf] * feat;
    } else if (t >= 64 && t < 64 + 4 * NQ_) {
        // set0 = U0(L0); set1 = U0(L1)*U1(L0); set2 = U0(L2)*U1(L1); set3 = U1(L2)
        int j = t - 64;
        int set = j / NQ_;
        int q = j - set * NQ_;
        auto build = [&](int l, int s, float2 Uo[4]) {
            const float* a = psq + ((l * 2 + s) * NQ_ + q) * 3;
            float phi = a[0], th = a[1], om = a[2];
            float sh, ch; sincosf(0.5f * th, &sh, &ch);
            float sa, ca; sincosf(0.5f * (phi + om), &sa, &ca);
            float sb, cb; sincosf(0.5f * (phi - om), &sb, &cb);
            Uo[0] = make_float2( ch * ca, -ch * sa);
            Uo[1] = make_float2(-sh * cb, -sh * sb);
            Uo[2] = make_float2( sh * cb, -sh * sb);
            Uo[3] = make_float2( ch * ca,  ch * sa);
        };
        float2 M[4];
        if (set == 0) {
            build(0, 0, M);
        } else if (set == 3) {
            build(2, 1, M);
        } else {
            float2 A[4], Bm[4];
            build(set, 0, A);        // second
            build(set - 1, 1, Bm);   // first
            M[0].x = A[0].x*Bm[0].x - A[0].y*Bm[0].y + A[1].x*Bm[2].x - A[1].y*Bm[2].y;
            M[0].y = A[0].x*Bm[0].y + A[0].y*Bm[0].x + A[1].x*Bm[2].y + A[1].y*Bm[2].x;
            M[1].x = A[0].x*Bm[1].x - A[0].y*Bm[1].y + A[1].x*Bm[3].x - A[1].y*Bm[3].y;
            M[1].y = A[0].x*Bm[1].y + A[0].y*Bm[1].x + A[1].x*Bm[3].y + A[1].y*Bm[3].x;
            M[2].x = A[2].x*Bm[0].x - A[2].y*Bm[0].y + A[3].x*Bm[2].x - A[3].y*Bm[2].y;
            M[2].y = A[2].x*Bm[0].y + A[2].y*Bm[0].x + A[3].x*Bm[2].y + A[3].y*Bm[2].x;
            M[3].x = A[2].x*Bm[1].x - A[2].y*Bm[1].y + A[3].x*Bm[3].x - A[3].y*Bm[3].y;
            M[3].y = A[2].x*Bm[1].y + A[2].y*Bm[1].x + A[3].x*Bm[3].y + A[3].y*Bm[3].x;
        }
        #pragma unroll
        for (int e = 0; e < 4; ++e) s_U[set][q][e] = M[e];
    }
    __syncthreads();

    // ---------- phase 2: diag cis tables (layers 0,1) + observable tables ----------
    if (t < 256) {
        int l = t >> 7, i = t & 127;
        float v = 0.0f;
        #pragma unroll
        for (int b = 0; b < 7; ++b)
            if ((i >> b) & 1) v += s_theta[l][12 - b];
        float sn, cs; sincosf(v, &sn, &cs);
        s_C0[l][i] = make_float2(cs, sn);
    } else if (t < 384) {
        int j = t - 256;
        int l = j >> 6, h = j & 63;
        float S = 0.0f;
        #pragma unroll
        for (int p = 0; p < NPAIR; ++p) S += s_theta[l][p];
        float v = -0.5f * S;
        #pragma unroll
        for (int b = 7; b < 13; ++b)
            if ((h >> (b - 7)) & 1) v += s_theta[l][12 - b];
        float sn, cs; sincosf(v, &sn, &cs);
        s_C1[l][h] = make_float2(cs, sn);
    } else if (t < 440) {
        // WE[bp][s] = 2 * W_bp * cis(dphi), W = set3-rotated off-diagonal coefficient
        int idx = t - 384, bp = idx >> 2, s = idx & 3;
        int q = 13 - bp;
        float2 v00 = s_U[3][q][0], v01 = s_U[3][q][1];
        float2 v10 = s_U[3][q][2], v11 = s_U[3][q][3];
        float cz = pcl[q], cx = pcl[bp];
        // t1 = conj(v00)*v01 - conj(v10)*v11 ; t2 = conj(v00)*v11 + conj(v10)*v01
        float t1x = (v00.x*v01.x + v00.y*v01.y) - (v10.x*v11.x + v10.y*v11.y);
        float t1y = (v00.x*v01.y - v00.y*v01.x) - (v10.x*v11.y - v10.y*v11.x);
        float t2x = (v00.x*v11.x + v00.y*v11.y) + (v10.x*v01.x + v10.y*v01.y);
        float t2y = (v00.x*v11.y - v00.y*v11.x) + (v10.x*v01.y - v10.y*v01.x);
        float Wx = cz*t1x + cx*t2x, Wy = cz*t1y + cx*t2y;
        float tha = (bp <= 12) ? s_theta[2][12 - bp] : 0.f;
        float thb = (bp >= 1)  ? s_theta[2][13 - bp] : 0.f;
        float dphi = tha * (1.f - 2.f*((s >> 1) & 1)) + thb * (1.f - 2.f*(s & 1));
        float sn, cs; sincosf(dphi, &sn, &cs);
        s_WE[bp][s] = make_float2(2.f*(Wx*cs - Wy*sn), 2.f*(Wx*sn + Wy*cs));
    } else if (t >= 448 && t < 462) {
        int bp = t - 448, q = 13 - bp;
        float2 v00 = s_U[3][q][0], v10 = s_U[3][q][2];
        float cz = pcl[q], cx = pcl[bp];
        s_G[bp] = cz * ((v00.x*v00.x + v00.y*v00.y) - (v10.x*v10.x + v10.y*v10.y))
                + 2.f*cx * (v00.x*v10.x + v00.y*v10.y);
    }
    __syncthreads();

    float2 a[16];
    float acc = 0.0f;

    // ---- layouts A(bits0-3), B(4-7), C(8-11), D(12,13,0,1), E(2,3,7,11) ----
#define LOAD_A() do { _Pragma("unroll") for (int c = 0; c < 8; ++c) { \
        int p = SW((t << 4) | (2*c)); \
        float4 v = *(const float4*)&s_amp[p]; \
        a[2*c] = make_float2(v.x, v.y); a[2*c+1] = make_float2(v.z, v.w); } } while (0)
#define STORE_A() do { _Pragma("unroll") for (int c = 0; c < 8; ++c) { \
        int p = SW((t << 4) | (2*c)); \
        *(float4*)&s_amp[p] = make_float4(a[2*c].x, a[2*c].y, a[2*c+1].x, a[2*c+1].y); } } while (0)
#define LOAD_B() do { int bb = ((t >> 4) << 8) | (t & 15); _Pragma("unroll") \
        for (int j = 0; j < 16; ++j) a[j] = s_amp[SW(bb | (j << 4))]; } while (0)
#define STORE_B() do { int bb = ((t >> 4) << 8) | (t & 15); _Pragma("unroll") \
        for (int j = 0; j < 16; ++j) s_amp[SW(bb | (j << 4))] = a[j]; } while (0)
#define LOAD_C() do { int bc = ((t >> 8) << 12) | (t & 255); _Pragma("unroll") \
        for (int j = 0; j < 16; ++j) a[j] = s_amp[SW(bc | (j << 8))]; } while (0)
#define STORE_C() do { int bc = ((t >> 8) << 12) | (t & 255); _Pragma("unroll") \
        for (int j = 0; j < 16; ++j) s_amp[SW(bc | (j << 8))] = a[j]; } while (0)
#define LOAD_D() do { _Pragma("unroll") for (int jh = 0; jh < 4; ++jh) \
        _Pragma("unroll") for (int c = 0; c < 2; ++c) { \
        int p = SW((jh << 12) | (t << 2) | (2*c)); \
        float4 v = *(const float4*)&s_amp[p]; \
        a[jh*4+2*c] = make_float2(v.x, v.y); a[jh*4+2*c+1] = make_float2(v.z, v.w); } } while (0)
#define STORE_D() do { _Pragma("unroll") for (int jh = 0; jh < 4; ++jh) \
        _Pragma("unroll") for (int c = 0; c < 2; ++c) { \
        int p = SW((jh << 12) | (t << 2) | (2*c)); \
        *(float4*)&s_amp[p] = make_float4(a[jh*4+2*c].x, a[jh*4+2*c].y, a[jh*4+2*c+1].x, a[jh*4+2*c+1].y); } } while (0)
#define LOAD_E() do { \
        int kb = (t & 3) | (((t >> 2) & 7) << 4) | (((t >> 5) & 7) << 8) | (((t >> 8) & 3) << 12); \
        _Pragma("unroll") for (int j = 0; j < 16; ++j) { \
            int k = kb | ((j & 3) << 2) | (((j >> 2) & 1) << 7) | (((j >> 3) & 1) << 11); \
            a[j] = s_amp[SW(k)]; } } while (0)

#define DIAG(l, KEXPR) do { _Pragma("unroll") for (int j = 0; j < 16; ++j) { \
        int k = (KEXPR); int m = k ^ (k >> 1); \
        float2 ph = cmul(s_C0[l][m & 127], s_C1[l][(m >> 7) & 63]); \
        a[j] = cmul(a[j], ph); } } while (0)

    // Measure bit bp at register bit RB: Z part (gamma) + phase-corrected X/Y part (WE).
    // |a|^2 computed inline per pair (no pr[16] array -> low register pressure, no spill).
    // NHI/NLO = values of state bits bp+1 / bp-1 (expressions in j and t).
#define MEAS(BP, RB, NHI, NLO) do { \
    float g = s_G[BP]; float zs = 0.f, xr = 0.f; \
    const float2* WEp = s_WE[BP]; \
    _Pragma("unroll") for (int j = 0; j < 16; ++j) { \
        if (!((j >> (RB)) & 1)) { \
            int j1 = j | (1 << (RB)); \
            float cr = a[j].x*a[j1].x + a[j].y*a[j1].y; \
            float ci = a[j].x*a[j1].y - a[j].y*a[j1].x; \
            float2 w = WEp[((NHI) << 1) | (NLO)]; \
            xr += w.x * cr - w.y * ci; \
            zs += (a[j].x*a[j].x + a[j].y*a[j].y) - (a[j1].x*a[j1].x + a[j1].y*a[j1].y); \
        } } \
    acc += g * zs + xr; \
} while (0)

    // ---- P1 (D): analytic set0 product state, diag0, set1 gates bits12,13 ----
    {
        float2 F = make_float2(1.f, 0.f);
        #pragma unroll
        for (int bp = 2; bp < 12; ++bp) {
            int b = (t >> (bp - 2)) & 1;
            float2 f = s_U[0][13 - bp][b ? 2 : 0];
            F = cmul(F, f);
        }
        float2 g01[4], g23[4];
        #pragma unroll
        for (int j1 = 0; j1 < 2; ++j1)
            #pragma unroll
            for (int j0 = 0; j0 < 2; ++j0)
                g01[(j1 << 1) | j0] = cmul(s_U[0][13][j0 ? 2 : 0], s_U[0][12][j1 ? 2 : 0]);
        #pragma unroll
        for (int j3 = 0; j3 < 2; ++j3)
            #pragma unroll
            for (int j2 = 0; j2 < 2; ++j2)
                g23[(j3 << 1) | j2] = cmul(s_U[0][1][j2 ? 2 : 0], s_U[0][0][j3 ? 2 : 0]);
        float2 Fg[4];
        #pragma unroll
        for (int jl = 0; jl < 4; ++jl) Fg[jl] = cmul(F, g01[jl]);
        #pragma unroll
        for (int j = 0; j < 16; ++j) a[j] = cmul(Fg[j & 3], g23[j >> 2]);
    }
    DIAG(0, ((j >> 2) << 12) | (t << 2) | (j & 3));
    GATE_BIT(2, s_U[1][1]);   // bit12 -> qubit 1
    GATE_BIT(3, s_U[1][0]);   // bit13 -> qubit 0
    STORE_D(); __syncthreads();

    // ---- P2 (C): set1 bits 8-11 ----
    LOAD_C();
    GATE_BIT(0, s_U[1][5]); GATE_BIT(1, s_U[1][4]);
    GATE_BIT(2, s_U[1][3]); GATE_BIT(3, s_U[1][2]);
    STORE_C(); __syncthreads();

    // ---- P3 (B): set1 bits 4-7 ----
    LOAD_B();
    GATE_BIT(0, s_U[1][9]); GATE_BIT(1, s_U[1][8]);
    GATE_BIT(2, s_U[1][7]); GATE_BIT(3, s_U[1][6]);
    STORE_B(); __syncthreads();

    // ---- P4 (A): set1 bits 0-3, diag1, set2 bits 0-3, measure bits 0-2 ----
    LOAD_A();
    GATE_BIT(0, s_U[1][13]); GATE_BIT(1, s_U[1][12]);
    GATE_BIT(2, s_U[1][11]); GATE_BIT(3, s_U[1][10]);
    DIAG(1, (t << 4) | j);
    GATE_BIT(0, s_U[2][13]); GATE_BIT(1, s_U[2][12]);
    GATE_BIT(2, s_U[2][11]); GATE_BIT(3, s_U[2][10]);
    MEAS(0, 0, ((j >> 1) & 1), 0);
    MEAS(1, 1, ((j >> 2) & 1), (j & 1));
    MEAS(2, 2, ((j >> 3) & 1), ((j >> 1) & 1));
    STORE_A(); __syncthreads();

    // ---- P5 (B): set2 bits 4-7, measure bits 4-6 ----
    LOAD_B();
    GATE_BIT(0, s_U[2][9]); GATE_BIT(1, s_U[2][8]);
    GATE_BIT(2, s_U[2][7]); GATE_BIT(3, s_U[2][6]);
    MEAS(4, 0, ((j >> 1) & 1), ((t >> 3) & 1));
    MEAS(5, 1, ((j >> 2) & 1), (j & 1));
    MEAS(6, 2, ((j >> 3) & 1), ((j >> 1) & 1));
    STORE_B(); __syncthreads();

    // ---- P6 (C): set2 bits 8-11, measure bits 8-10 ----
    LOAD_C();
    GATE_BIT(0, s_U[2][5]); GATE_BIT(1, s_U[2][4]);
    GATE_BIT(2, s_U[2][3]); GATE_BIT(3, s_U[2][2]);
    MEAS(8, 0, ((j >> 1) & 1), ((t >> 7) & 1));
    MEAS(9, 1, ((j >> 2) & 1), (j & 1));
    MEAS(10, 2, ((j >> 3) & 1), ((j >> 1) & 1));
    STORE_C(); __syncthreads();

    // ---- P7 (D): set2 bits 12,13, measure bits 12,13 ----
    LOAD_D();
    GATE_BIT(2, s_U[2][1]); GATE_BIT(3, s_U[2][0]);
    MEAS(12, 2, ((j >> 3) & 1), ((t >> 9) & 1));
    MEAS(13, 3, 0, ((j >> 2) & 1));
    STORE_D(); __syncthreads();

    // ---- P8 (E: bits 2,3,7,11): measure bits 3,7,11 (load only) ----
    LOAD_E();
    MEAS(3,  1, ((t >> 2) & 1), (j & 1));
    MEAS(7,  2, ((t >> 5) & 1), ((t >> 4) & 1));
    MEAS(11, 3, ((t >> 8) & 1), ((t >> 7) & 1));

    // ---- block reduction ----
    #pragma unroll
    for (int off = 32; off > 0; off >>= 1)
        acc += __shfl_down(acc, off);
    if ((t & 63) == 0) s_red[t >> 6] = acc;
    __syncthreads();
    if (t == 0) {
        float s = 0.0f;
        #pragma unroll
        for (int w = 0; w < 16; ++w) s += s_red[w];
        out[n] = s;
    }
}

extern "C" void kernel_launch(void* const* d_in, const int* in_sizes, int n_in,
                              void* d_out, int out_size, void* d_ws, size_t ws_size,
                              hipStream_t stream) {
    const float* x    = (const float*)d_in[0];
    const float* psq  = (const float*)d_in[1];
    const float* p2q  = (const float*)d_in[2];
    const float* penc = (const float*)d_in[3];
    const float* pcl  = (const float*)d_in[4];
    float* out = (float*)d_out;
    pqc_kernel<<<NB, NT, 0, stream>>>(x, psq, p2q, penc, pcl, out);
}